// Round 6
// baseline (252.365 us; speedup 1.0000x reference)
//
#include <hip/hip_runtime.h>

// SelfAttention: S=4096, EMB=2048, DQ=DV=2048, causal softmax(QK^T/sqrt(DQ))V
// Round 6: (a) QKV split into QK (512 blocks, 2 exact rounds) + V^T (256
// blocks) so V^T overlaps S-GEMM's 16-block straggler round; (b) PV gets a
// balanced-pair block->tile map (co-resident pairs sum to constant K-work).

using u16 = unsigned short;
typedef __bf16 bf16x8 __attribute__((ext_vector_type(8)));
typedef float  f32x4  __attribute__((ext_vector_type(4)));
typedef u16    u16x8  __attribute__((ext_vector_type(8)));

__device__ __forceinline__ u16 f2b(float f) {
  union { float f; unsigned u; } x; x.f = f;
  unsigned r = x.u + 0x7fffu + ((x.u >> 16) & 1u);  // RNE
  return (u16)(r >> 16);
}
__device__ __forceinline__ float b2f(u16 h) {
  union { unsigned u; float f; } x; x.u = ((unsigned)h) << 16;
  return x.f;
}

#define GLL16(src, dst)                                                        \
  __builtin_amdgcn_global_load_lds(                                            \
      (const __attribute__((address_space(1))) void*)(src),                    \
      (__attribute__((address_space(3))) void*)(dst), 16, 0, 0)

#define MFMA_BF16(a, b, c) __builtin_amdgcn_mfma_f32_16x16x32_bf16(a, b, c, 0, 0, 0)

// One fused cast: regions are block-aligned (2048 elems/block).
__global__ __launch_bounds__(256)
void cast_all(const float* __restrict__ x, const float* __restrict__ wq,
              const float* __restrict__ wk, const float* __restrict__ wv,
              u16* __restrict__ dst) {
  const int b = blockIdx.x;  // 10240 blocks
  const float* src;
  size_t off;
  if (b < 4096)      { src = x;  off = (size_t)b * 2048; }
  else if (b < 6144) { src = wq; off = (size_t)(b - 4096) * 2048; }
  else if (b < 8192) { src = wk; off = (size_t)(b - 6144) * 2048; }
  else               { src = wv; off = (size_t)(b - 8192) * 2048; }
  const size_t e = off + (size_t)threadIdx.x * 8;
  float4 a = *(const float4*)(src + e);
  float4 c = *(const float4*)(src + e + 4);
  u16x8 o;
  o[0] = f2b(a.x); o[1] = f2b(a.y); o[2] = f2b(a.z); o[3] = f2b(a.w);
  o[4] = f2b(c.x); o[5] = f2b(c.y); o[6] = f2b(c.z); o[7] = f2b(c.w);
  *(u16x8*)(dst + (size_t)b * 2048 + (size_t)threadIdx.x * 8) = o;
}

// ---------------------------------------------------------------------------
// QKV projection slice: [Q|K|V^T] = x(4096x2048) . W^T(6144x2048).
// Tile 256x128, BK=64, 8 waves 4Mx2N, 96KB LDS, read-ahead pipeline with
// counted vmcnt(6), T2 swizzle. bn_base selects the column-block range so the
// projection can be launched as QK (bn 0..31) and V^T (bn 32..47) separately.
// ---------------------------------------------------------------------------
__global__ __launch_bounds__(512)
void gemm_qkv(const u16* __restrict__ A, const u16* __restrict__ W,
              u16* __restrict__ Qo, u16* __restrict__ Ko,
              u16* __restrict__ VTo, int bn_base) {
  extern __shared__ char lds[];
  constexpr int NT = 32;  // 2048/64
  const int bn = blockIdx.x + bn_base, bm = blockIdx.y;
  const int tid = threadIdx.x;
  const int w = tid >> 6, lane = tid & 63;
  const int wr = w >> 1, wc = w & 1;
  const int l15 = lane & 15, l4 = lane >> 4;
  const int rs = lane >> 3;
  const int csw = ((lane & 7) ^ rs) << 3;
  const int m0 = bm * 256, n0 = bn * 128;

  const u16* gA = A + (size_t)(m0 + w * 8 + rs) * 2048 + csw;
  const u16* gB = W + (size_t)(n0 + w * 8 + rs) * 2048 + csw;
  char* lw = lds + w * 1024;
  const u16* sm = (const u16*)lds;

  auto stA = [&](int p, int u, int tt) {
    GLL16(gA + (size_t)u * 64 * 2048 + tt * 64, lw + p * 49152 + u * 8192);
  };
  auto stB = [&](int p, int u, int tt) {
    GLL16(gB + (size_t)u * 64 * 2048 + tt * 64, lw + p * 49152 + 32768 + u * 8192);
  };
  const int swz = (l15 & 7) << 3;
  auto rdA = [&](int p, int m, int kk) -> bf16x8 {
    int e = p * 24576 + wr * 4096 + (((m * 16 + l15) * 64 + kk * 32 + l4 * 8) ^ swz);
    return *(const bf16x8*)&sm[e];
  };
  auto rdB = [&](int p, int n, int kk) -> bf16x8 {
    int e = p * 24576 + 16384 + wc * 4096 +
            (((n * 16 + l15) * 64 + kk * 32 + l4 * 8) ^ swz);
    return *(const bf16x8*)&sm[e];
  };

  f32x4 acc[4][4] = {};
  bf16x8 aE[4][2], aO[4][2], b01E[2][2], b01O[2][2], b23E[2][2], b23O[2][2];

  stA(0,0,0); stA(0,1,0); stA(0,2,0); stA(0,3,0); stB(0,0,0); stB(0,1,0);
  stA(1,0,1); stA(1,1,1); stA(1,2,1); stA(1,3,1); stB(1,0,1); stB(1,1,1);
  asm volatile("s_waitcnt vmcnt(6)" ::: "memory");
  __builtin_amdgcn_sched_barrier(0);
  __builtin_amdgcn_s_barrier();
#pragma unroll
  for (int m = 0; m < 4; ++m) { aE[m][0] = rdA(0,m,0); aE[m][1] = rdA(0,m,1); }
#pragma unroll
  for (int n = 0; n < 2; ++n) { b01E[n][0] = rdB(0,n,0); b01E[n][1] = rdB(0,n,1); }
  asm volatile("s_waitcnt lgkmcnt(0)" ::: "memory");
  __builtin_amdgcn_sched_barrier(0);
  __builtin_amdgcn_s_barrier();

  for (int i = 0; i < NT / 2; ++i) {
    const int te = 2 * i, to = 2 * i + 1;
    // tile te (buf0) ph0
    if (te + 2 < NT) { stA(0,0,te+2); stA(0,1,te+2); stA(0,2,te+2); }
#pragma unroll
    for (int n = 0; n < 2; ++n) { b23E[n][0] = rdB(0,n+2,0); b23E[n][1] = rdB(0,n+2,1); }
    __builtin_amdgcn_s_barrier();
    __builtin_amdgcn_s_setprio(1);
#pragma unroll
    for (int m = 0; m < 4; ++m)
#pragma unroll
      for (int n = 0; n < 2; ++n)
#pragma unroll
        for (int kk = 0; kk < 2; ++kk)
          acc[m][n] = MFMA_BF16(aE[m][kk], b01E[n][kk], acc[m][n]);
    __builtin_amdgcn_s_setprio(0);
    asm volatile("s_waitcnt lgkmcnt(0)" ::: "memory");
    __builtin_amdgcn_sched_barrier(0);
    __builtin_amdgcn_s_barrier();
    // tile te ph1
    if (te + 2 < NT) {
      stA(0,3,te+2); stB(0,0,te+2); stB(0,1,te+2);
      asm volatile("s_waitcnt vmcnt(6)" ::: "memory");
    } else {
      asm volatile("s_waitcnt vmcnt(0)" ::: "memory");
    }
    __builtin_amdgcn_sched_barrier(0);
    __builtin_amdgcn_s_barrier();
#pragma unroll
    for (int m = 0; m < 4; ++m) { aO[m][0] = rdA(1,m,0); aO[m][1] = rdA(1,m,1); }
#pragma unroll
    for (int n = 0; n < 2; ++n) { b01O[n][0] = rdB(1,n,0); b01O[n][1] = rdB(1,n,1); }
    __builtin_amdgcn_s_setprio(1);
#pragma unroll
    for (int m = 0; m < 4; ++m)
#pragma unroll
      for (int n = 0; n < 2; ++n)
#pragma unroll
        for (int kk = 0; kk < 2; ++kk)
          acc[m][n+2] = MFMA_BF16(aE[m][kk], b23E[n][kk], acc[m][n+2]);
    __builtin_amdgcn_s_setprio(0);
    asm volatile("s_waitcnt lgkmcnt(0)" ::: "memory");
    __builtin_amdgcn_sched_barrier(0);
    __builtin_amdgcn_s_barrier();
    // tile to (buf1) ph0
    if (to + 2 < NT) { stA(1,0,to+2); stA(1,1,to+2); stA(1,2,to+2); }
#pragma unroll
    for (int n = 0; n < 2; ++n) { b23O[n][0] = rdB(1,n+2,0); b23O[n][1] = rdB(1,n+2,1); }
    __builtin_amdgcn_s_barrier();
    __builtin_amdgcn_s_setprio(1);
#pragma unroll
    for (int m = 0; m < 4; ++m)
#pragma unroll
      for (int n = 0; n < 2; ++n)
#pragma unroll
        for (int kk = 0; kk < 2; ++kk)
          acc[m][n] = MFMA_BF16(aO[m][kk], b01O[n][kk], acc[m][n]);
    __builtin_amdgcn_s_setprio(0);
    asm volatile("s_waitcnt lgkmcnt(0)" ::: "memory");
    __builtin_amdgcn_sched_barrier(0);
    __builtin_amdgcn_s_barrier();
    // tile to ph1
    if (to + 2 < NT) {
      stA(1,3,to+2); stB(1,0,to+2); stB(1,1,to+2);
      asm volatile("s_waitcnt vmcnt(6)" ::: "memory");
    } else if (to + 1 < NT) {
      asm volatile("s_waitcnt vmcnt(0)" ::: "memory");
    }
    __builtin_amdgcn_sched_barrier(0);
    __builtin_amdgcn_s_barrier();
    if (to + 1 < NT) {
#pragma unroll
      for (int m = 0; m < 4; ++m) { aE[m][0] = rdA(0,m,0); aE[m][1] = rdA(0,m,1); }
#pragma unroll
      for (int n = 0; n < 2; ++n) { b01E[n][0] = rdB(0,n,0); b01E[n][1] = rdB(0,n,1); }
    }
    __builtin_amdgcn_s_setprio(1);
#pragma unroll
    for (int m = 0; m < 4; ++m)
#pragma unroll
      for (int n = 0; n < 2; ++n)
#pragma unroll
        for (int kk = 0; kk < 2; ++kk)
          acc[m][n+2] = MFMA_BF16(aO[m][kk], b23O[n][kk], acc[m][n+2]);
    __builtin_amdgcn_s_setprio(0);
    asm volatile("s_waitcnt lgkmcnt(0)" ::: "memory");
    __builtin_amdgcn_sched_barrier(0);
    __builtin_amdgcn_s_barrier();
  }

  const int row0 = m0 + wr * 64 + l4 * 4;
  const int cg0 = n0 + wc * 64 + l15;
  if (bn < 16) {
#pragma unroll
    for (int m = 0; m < 4; ++m)
#pragma unroll
      for (int n = 0; n < 4; ++n)
#pragma unroll
        for (int j = 0; j < 4; ++j)
          Qo[(size_t)(row0 + m * 16 + j) * 2048 + cg0 + n * 16] = f2b(acc[m][n][j]);
  } else if (bn < 32) {
#pragma unroll
    for (int m = 0; m < 4; ++m)
#pragma unroll
      for (int n = 0; n < 4; ++n)
#pragma unroll
        for (int j = 0; j < 4; ++j)
          Ko[(size_t)(row0 + m * 16 + j) * 2048 + (cg0 + n * 16 - 2048)] = f2b(acc[m][n][j]);
  } else {
#pragma unroll
    for (int m = 0; m < 4; ++m)
#pragma unroll
      for (int n = 0; n < 4; ++n)
#pragma unroll
        for (int j = 0; j < 4; ++j)
          VTo[(size_t)(cg0 + n * 16 - 4096) * 4096 + row0 + m * 16 + j] = f2b(acc[m][n][j]);
  }
}

// ---------------------------------------------------------------------------
// pipe128: read-ahead pipeline at 128x128 tile, 4 waves (2Mx2N), BK=64,
// 64KB LDS double-buffered (2 blocks/CU).
// MODE 0: S = alpha * Q . K^T  (bf16 out, compact triangular grid 528)
// MODE 1: O = P . V            (f32 out, K-clamp, balanced-pair grid 512:
//         blocks i and i+256 map to complementary row weights so likely
//         co-resident pairs sum to a constant 66 K-tiles per CU)
// ---------------------------------------------------------------------------
template<int MODE>
__global__ __launch_bounds__(256)
void pipe128(const u16* __restrict__ A, const u16* __restrict__ B,
             void* __restrict__ C, float alpha) {
  extern __shared__ char lds[];
  constexpr int LDA = (MODE == 0) ? 2048 : 4096;
  constexpr int LDB = (MODE == 0) ? 2048 : 4096;

  int bm, bn;
  if (MODE == 0) {
    const int b = blockIdx.x;  // 528 causal tiles, bn <= bm
    int r = (int)((sqrtf(8.f * (float)b + 1.f) - 1.f) * 0.5f);
    while ((r + 1) * (r + 2) / 2 <= b) ++r;
    while (r * (r + 1) / 2 > b) --r;
    bm = r; bn = b - r * (r + 1) / 2;
  } else {
    const int b = blockIdx.x;  // 512; balanced pairing (i, i+256)
    bm = (b < 256) ? (b >> 4) : (31 - ((b - 256) >> 4));
    bn = b & 15;
  }
  const int NT = (MODE == 0) ? 32 : 2 * (bm + 1);  // K-tiles of 64 (even, >=2)

  const int tid = threadIdx.x;
  const int w = tid >> 6, lane = tid & 63;
  const int wr = w >> 1, wc = w & 1;
  const int l15 = lane & 15, l4 = lane >> 4;
  const int rs = lane >> 3;
  const int csw = ((lane & 7) ^ rs) << 3;
  const int m0 = bm * 128, n0 = bn * 128;

  const u16* gA = A + (size_t)(m0 + w * 8 + rs) * LDA + csw;
  const u16* gB = B + (size_t)(n0 + w * 8 + rs) * LDB + csw;
  char* lw = lds + w * 1024;
  const u16* sm = (const u16*)lds;

  auto stA = [&](int p, int u, int tt) {  // A unit u = 32 rows
    GLL16(gA + (size_t)(u * 32) * LDA + tt * 64, lw + p * 32768 + u * 4096);
  };
  auto stB = [&](int p, int u, int tt) {
    GLL16(gB + (size_t)(u * 32) * LDB + tt * 64, lw + p * 32768 + 16384 + u * 4096);
  };
  const int swz = (l15 & 7) << 3;
  auto rdA = [&](int p, int m, int kk) -> bf16x8 {
    int e = p * 16384 + wr * 4096 + (((m * 16 + l15) * 64 + kk * 32 + l4 * 8) ^ swz);
    return *(const bf16x8*)&sm[e];
  };
  auto rdB = [&](int p, int n, int kk) -> bf16x8 {
    int e = p * 16384 + 8192 + wc * 4096 +
            (((n * 16 + l15) * 64 + kk * 32 + l4 * 8) ^ swz);
    return *(const bf16x8*)&sm[e];
  };

  f32x4 acc[4][4] = {};
  bf16x8 aE[4][2], aO[4][2], b01E[2][2], b01O[2][2], b23E[2][2], b23O[2][2];

  stA(0,0,0); stA(0,1,0); stA(0,2,0); stA(0,3,0);
  stB(0,0,0); stB(0,1,0); stB(0,2,0); stB(0,3,0);
  stA(1,0,1); stA(1,1,1); stA(1,2,1); stA(1,3,1);
  stB(1,0,1); stB(1,1,1); stB(1,2,1); stB(1,3,1);
  asm volatile("s_waitcnt vmcnt(8)" ::: "memory");
  __builtin_amdgcn_sched_barrier(0);
  __builtin_amdgcn_s_barrier();
#pragma unroll
  for (int m = 0; m < 4; ++m) { aE[m][0] = rdA(0,m,0); aE[m][1] = rdA(0,m,1); }
#pragma unroll
  for (int n = 0; n < 2; ++n) { b01E[n][0] = rdB(0,n,0); b01E[n][1] = rdB(0,n,1); }
  asm volatile("s_waitcnt lgkmcnt(0)" ::: "memory");
  __builtin_amdgcn_sched_barrier(0);
  __builtin_amdgcn_s_barrier();

  for (int i = 0; i < (NT >> 1); ++i) {
    const int te = 2 * i, to = 2 * i + 1;
    // ---- tile te (buf0) ph0 ----
    if (te + 2 < NT) { stA(0,0,te+2); stA(0,1,te+2); stA(0,2,te+2); stA(0,3,te+2); }
#pragma unroll
    for (int n = 0; n < 2; ++n) { b23E[n][0] = rdB(0,n+2,0); b23E[n][1] = rdB(0,n+2,1); }
    __builtin_amdgcn_s_barrier();
    __builtin_amdgcn_s_setprio(1);
#pragma unroll
    for (int m = 0; m < 4; ++m)
#pragma unroll
      for (int n = 0; n < 2; ++n)
#pragma unroll
        for (int kk = 0; kk < 2; ++kk)
          acc[m][n] = MFMA_BF16(aE[m][kk], b01E[n][kk], acc[m][n]);
    __builtin_amdgcn_s_setprio(0);
    asm volatile("s_waitcnt lgkmcnt(0)" ::: "memory");
    __builtin_amdgcn_sched_barrier(0);
    __builtin_amdgcn_s_barrier();
    // ---- tile te ph1 ----
    if (te + 2 < NT) {
      stB(0,0,te+2); stB(0,1,te+2); stB(0,2,te+2); stB(0,3,te+2);
      asm volatile("s_waitcnt vmcnt(8)" ::: "memory");
    } else {
      asm volatile("s_waitcnt vmcnt(0)" ::: "memory");
    }
    __builtin_amdgcn_sched_barrier(0);
    __builtin_amdgcn_s_barrier();
#pragma unroll
    for (int m = 0; m < 4; ++m) { aO[m][0] = rdA(1,m,0); aO[m][1] = rdA(1,m,1); }
#pragma unroll
    for (int n = 0; n < 2; ++n) { b01O[n][0] = rdB(1,n,0); b01O[n][1] = rdB(1,n,1); }
    __builtin_amdgcn_s_setprio(1);
#pragma unroll
    for (int m = 0; m < 4; ++m)
#pragma unroll
      for (int n = 0; n < 2; ++n)
#pragma unroll
        for (int kk = 0; kk < 2; ++kk)
          acc[m][n+2] = MFMA_BF16(aE[m][kk], b23E[n][kk], acc[m][n+2]);
    __builtin_amdgcn_s_setprio(0);
    asm volatile("s_waitcnt lgkmcnt(0)" ::: "memory");
    __builtin_amdgcn_sched_barrier(0);
    __builtin_amdgcn_s_barrier();
    // ---- tile to (buf1) ph0 ----
    if (to + 2 < NT) { stA(1,0,to+2); stA(1,1,to+2); stA(1,2,to+2); stA(1,3,to+2); }
#pragma unroll
    for (int n = 0; n < 2; ++n) { b23O[n][0] = rdB(1,n+2,0); b23O[n][1] = rdB(1,n+2,1); }
    __builtin_amdgcn_s_barrier();
    __builtin_amdgcn_s_setprio(1);
#pragma unroll
    for (int m = 0; m < 4; ++m)
#pragma unroll
      for (int n = 0; n < 2; ++n)
#pragma unroll
        for (int kk = 0; kk < 2; ++kk)
          acc[m][n] = MFMA_BF16(aO[m][kk], b01O[n][kk], acc[m][n]);
    __builtin_amdgcn_s_setprio(0);
    asm volatile("s_waitcnt lgkmcnt(0)" ::: "memory");
    __builtin_amdgcn_sched_barrier(0);
    __builtin_amdgcn_s_barrier();
    // ---- tile to ph1 ----
    if (to + 2 < NT) {
      stB(1,0,to+2); stB(1,1,to+2); stB(1,2,to+2); stB(1,3,to+2);
      asm volatile("s_waitcnt vmcnt(8)" ::: "memory");
    } else if (to + 1 < NT) {
      asm volatile("s_waitcnt vmcnt(0)" ::: "memory");
    }
    __builtin_amdgcn_sched_barrier(0);
    __builtin_amdgcn_s_barrier();
    if (to + 1 < NT) {
#pragma unroll
      for (int m = 0; m < 4; ++m) { aE[m][0] = rdA(0,m,0); aE[m][1] = rdA(0,m,1); }
#pragma unroll
      for (int n = 0; n < 2; ++n) { b01E[n][0] = rdB(0,n,0); b01E[n][1] = rdB(0,n,1); }
    }
    __builtin_amdgcn_s_setprio(1);
#pragma unroll
    for (int m = 0; m < 4; ++m)
#pragma unroll
      for (int n = 0; n < 2; ++n)
#pragma unroll
        for (int kk = 0; kk < 2; ++kk)
          acc[m][n+2] = MFMA_BF16(aO[m][kk], b23O[n][kk], acc[m][n+2]);
    __builtin_amdgcn_s_setprio(0);
    asm volatile("s_waitcnt lgkmcnt(0)" ::: "memory");
    __builtin_amdgcn_sched_barrier(0);
    __builtin_amdgcn_s_barrier();
  }

  const int row0 = m0 + wr * 64 + l4 * 4;
  const int col0 = n0 + wc * 64 + l15;
  if (MODE == 0) {
    u16* Co = (u16*)C;
#pragma unroll
    for (int m = 0; m < 4; ++m)
#pragma unroll
      for (int n = 0; n < 4; ++n)
#pragma unroll
        for (int j = 0; j < 4; ++j)
          Co[(size_t)(row0 + m * 16 + j) * 4096 + col0 + n * 16] =
              f2b(acc[m][n][j] * alpha);
  } else {
    float* Co = (float*)C;
#pragma unroll
    for (int m = 0; m < 4; ++m)
#pragma unroll
      for (int n = 0; n < 4; ++n)
#pragma unroll
        for (int j = 0; j < 4; ++j)
          Co[(size_t)(row0 + m * 16 + j) * 2048 + col0 + n * 16] = acc[m][n][j];
  }
}

// In-place causal row softmax over bf16 [4096][4096]; writes 0 above diagonal.
__global__ __launch_bounds__(256)
void softmax_causal(u16* __restrict__ S) {
  const int i = blockIdx.x;
  const int t = threadIdx.x;
  u16* row = S + (size_t)i * 4096;

  u16x8 r0 = *(const u16x8*)(row + t * 16);
  u16x8 r1 = *(const u16x8*)(row + t * 16 + 8);

  float v[16];
  float mx = -__builtin_inff();
#pragma unroll
  for (int c = 0; c < 16; ++c) {
    int j = t * 16 + c;
    float x = b2f(c < 8 ? r0[c] : r1[c - 8]);
    v[c] = (j <= i) ? x : -__builtin_inff();
    mx = fmaxf(mx, v[c]);
  }
#pragma unroll
  for (int off = 32; off >= 1; off >>= 1) mx = fmaxf(mx, __shfl_xor(mx, off));
  __shared__ float red[8];
  if ((t & 63) == 0) red[t >> 6] = mx;
  __syncthreads();
  mx = fmaxf(fmaxf(red[0], red[1]), fmaxf(red[2], red[3]));

  float s = 0.f;
#pragma unroll
  for (int c = 0; c < 16; ++c) {
    float e = exp2f((v[c] - mx) * 1.4426950408889634f);
    v[c] = e;
    s += e;
  }
#pragma unroll
  for (int off = 32; off >= 1; off >>= 1) s += __shfl_xor(s, off);
  if ((t & 63) == 0) red[4 + (t >> 6)] = s;
  __syncthreads();
  s = red[4] + red[5] + red[6] + red[7];
  float inv = 1.0f / s;

  u16x8 o0, o1;
#pragma unroll
  for (int c = 0; c < 8; ++c) {
    o0[c] = f2b(v[c] * inv);
    o1[c] = f2b(v[c + 8] * inv);
  }
  *(u16x8*)(row + t * 16) = o0;
  *(u16x8*)(row + t * 16 + 8) = o1;
}

extern "C" void kernel_launch(void* const* d_in, const int* in_sizes, int n_in,
                              void* d_out, int out_size, void* d_ws, size_t ws_size,
                              hipStream_t stream) {
  const float* x  = (const float*)d_in[0];
  const float* wq = (const float*)d_in[1];
  const float* wk = (const float*)d_in[2];
  const float* wv = (const float*)d_in[3];

  // workspace layout (bf16 elements); x|wq|wk|wv contiguous for fused cast
  u16* x_bf  = (u16*)d_ws;
  u16* wq_bf = x_bf  + (size_t)4096 * 2048;
  u16* K_bf  = wq_bf + (size_t)3 * 2048 * 2048;
  u16* VT_bf = K_bf  + (size_t)4096 * 2048;
  u16* S_bf  = VT_bf + (size_t)2048 * 4096;
  u16* Q_bf  = (u16*)d_out;  // Q parked in d_out; dead before PV overwrites

  const float alpha = 0.022097086912079612f;  // 1/sqrt(2048)

  cast_all<<<dim3(10240), 256, 0, stream>>>(x, wq, wk, wv, x_bf);

  // [Q|K] = x . Wqk^T : bn 0..31, grid 512 = 2 exact rounds at 1 block/CU
  gemm_qkv<<<dim3(32, 16), 512, 98304, stream>>>(x_bf, wq_bf, Q_bf, K_bf, VT_bf, 0);
  // S = alpha * Q . K^T, compact causal grid (528 blocks, 2/CU)
  pipe128<0><<<dim3(528), 256, 65536, stream>>>(Q_bf, K_bf, S_bf, alpha);
  // V^T = (x . Wv^T)^T : bn 32..47, 256 blocks — fills S's straggler round
  gemm_qkv<<<dim3(16, 16), 512, 98304, stream>>>(x_bf, wq_bf, Q_bf, K_bf, VT_bf, 32);
  // row softmax with causal mask, in place
  softmax_causal<<<dim3(4096), 256, 0, stream>>>(S_bf);
  // O = P . V, K-clamped, balanced-pair grid (512 blocks)
  pipe128<1><<<dim3(512), 256, 65536, stream>>>(S_bf, VT_bf, d_out, 1.0f);
}